// Round 1
// baseline (113.252 us; speedup 1.0000x reference)
//
#include <hip/hip_runtime.h>

// ExpertCompoundTracker: MoE load-EMA + pairwise co-activation histogram.
// Inputs (setup order): expert_indices [N,K] int32, expert_weights [N,K] f32 (UNUSED),
//                       expert_load_ema [E] f32, expert_pair_coactivation [E,E] f32.
// Outputs concat: new_load_ema [64] then new_coact [4096], f32.

#define N_TOKENS   2097152
#define TOP_K      4
#define NUM_EXPERTS 64
#define NCELLS     (NUM_EXPERTS * NUM_EXPERTS)  // 4096

__global__ __launch_bounds__(256) void coact_accum_kernel(
    const int* __restrict__ idx, int* __restrict__ ws)
{
    __shared__ int s_coact[NCELLS];  // 16 KB per block
    for (int i = threadIdx.x; i < NCELLS; i += 256) s_coact[i] = 0;
    __syncthreads();

    const int tid    = blockIdx.x * 256 + threadIdx.x;
    const int stride = gridDim.x * 256;
    const int4* __restrict__ idx4 = (const int4*)idx;  // one token = 4 int32 = 16 B

    for (int t = tid; t < N_TOKENS; t += stride) {
        int4 v = idx4[t];
        const int e0 = v.x, e1 = v.y, e2 = v.z, e3 = v.w;
        // 6 unordered pairs, symmetric increments (12 LDS atomics/token).
        atomicAdd(&s_coact[e0 * 64 + e1], 1); atomicAdd(&s_coact[e1 * 64 + e0], 1);
        atomicAdd(&s_coact[e0 * 64 + e2], 1); atomicAdd(&s_coact[e2 * 64 + e0], 1);
        atomicAdd(&s_coact[e0 * 64 + e3], 1); atomicAdd(&s_coact[e3 * 64 + e0], 1);
        atomicAdd(&s_coact[e1 * 64 + e2], 1); atomicAdd(&s_coact[e2 * 64 + e1], 1);
        atomicAdd(&s_coact[e1 * 64 + e3], 1); atomicAdd(&s_coact[e3 * 64 + e1], 1);
        atomicAdd(&s_coact[e2 * 64 + e3], 1); atomicAdd(&s_coact[e3 * 64 + e2], 1);
    }
    __syncthreads();

    // Flush block-private histogram to global workspace (int, device-scope atomics).
    for (int i = threadIdx.x; i < NCELLS; i += 256) {
        int v = s_coact[i];
        if (v) atomicAdd(&ws[i], v);
    }
}

__global__ __launch_bounds__(256) void finalize_kernel(
    const int* __restrict__ ws,
    const float* __restrict__ ema_in,
    const float* __restrict__ coact_in,
    float* __restrict__ out)
{
    const int t = threadIdx.x;

    // new_coact = coact_in + delta  (delta integer-exact, values < 2^24)
    for (int i = t; i < NCELLS; i += 256) {
        out[NUM_EXPERTS + i] = coact_in[i] + (float)ws[i];
    }

    // counts[e] = row_sum(coact_delta[e]) / 3, exactly:
    // each occurrence of expert e in a token contributes +3 to row e
    // (pairs with the other 3 slots; duplicate-expert tokens included).
    if (t < NUM_EXPERTS) {
        int rowsum = 0;
        const int* row = ws + t * NUM_EXPERTS;
        #pragma unroll
        for (int b = 0; b < NUM_EXPERTS; ++b) rowsum += row[b];
        const int count = rowsum / 3;
        const float load = (float)count / (float)N_TOKENS;
        const float decay = (float)0.99;
        const float one_minus = (float)(1.0 - 0.99);  // match numpy double->f32
        out[t] = ema_in[t] * decay + load * one_minus;
    }
}

extern "C" void kernel_launch(void* const* d_in, const int* in_sizes, int n_in,
                              void* d_out, int out_size, void* d_ws, size_t ws_size,
                              hipStream_t stream)
{
    const int*   idx      = (const int*)d_in[0];
    // d_in[1] = expert_weights: unused by the reference -> never read (saves 32 MB).
    const float* ema_in   = (const float*)d_in[2];
    const float* coact_in = (const float*)d_in[3];
    float*       out      = (float*)d_out;
    int*         ws       = (int*)d_ws;

    // ws is poisoned 0xAA before every timed launch — zero it ourselves.
    hipMemsetAsync(ws, 0, NCELLS * sizeof(int), stream);

    // 512 blocks x 256 threads: 2 blocks/CU, 16 tokens/thread,
    // flush = 512 atomics/cell (cheap vs 8.4M if done per-token).
    coact_accum_kernel<<<512, 256, 0, stream>>>(idx, ws);
    finalize_kernel<<<1, 256, 0, stream>>>(ws, ema_in, coact_in, out);
}

// Round 2
// 110.701 us; speedup vs baseline: 1.0230x; 1.0230x over previous
//
#include <hip/hip_runtime.h>

// ExpertCompoundTracker: MoE load-EMA + pairwise co-activation histogram.
// Inputs (setup order): expert_indices [N,K] int32, expert_weights [N,K] f32 (UNUSED),
//                       expert_load_ema [E] f32, expert_pair_coactivation [E,E] f32.
// Outputs concat: new_load_ema [64] then new_coact [4096], f32.
//
// R2: upper-triangle-only accumulation. The symmetric co-activation update is
// redundant: ws[min,max] holds the unordered-pair count; finalize mirrors it
// (delta[i][j] = ws[min(i,j)][max(i,j)], diagonal x2). This halves the LDS
// atomics (12 -> 6 per token), which R1 showed is the bottleneck
// (~1 LDS atomic lane-op/cycle/CU => accum ~40us at 12/token).

#define N_TOKENS    2097152
#define TOP_K       4
#define NUM_EXPERTS 64
#define NCELLS      (NUM_EXPERTS * NUM_EXPERTS)  // 4096

__device__ __forceinline__ void pair_add(int* s, int a, int b) {
    const int lo = min(a, b), hi = max(a, b);
    atomicAdd(&s[lo * NUM_EXPERTS + hi], 1);
}

__global__ __launch_bounds__(256) void coact_accum_kernel(
    const int* __restrict__ idx, int* __restrict__ ws)
{
    __shared__ int s_coact[NCELLS];  // 16 KB; only upper triangle (i<=j) touched
    for (int i = threadIdx.x; i < NCELLS; i += 256) s_coact[i] = 0;
    __syncthreads();

    const int tid    = blockIdx.x * 256 + threadIdx.x;
    const int stride = gridDim.x * 256;
    const int4* __restrict__ idx4 = (const int4*)idx;  // one token = 4 int32 = 16 B

    for (int t = tid; t < N_TOKENS; t += stride) {
        int4 v = idx4[t];
        // 6 unordered pairs -> 6 LDS atomics/token (was 12 symmetric).
        pair_add(s_coact, v.x, v.y);
        pair_add(s_coact, v.x, v.z);
        pair_add(s_coact, v.x, v.w);
        pair_add(s_coact, v.y, v.z);
        pair_add(s_coact, v.y, v.w);
        pair_add(s_coact, v.z, v.w);
    }
    __syncthreads();

    // Flush. Lower-triangle cells are always 0 -> if(v) skips them
    // (~2080 global atomics/block instead of 4096).
    for (int i = threadIdx.x; i < NCELLS; i += 256) {
        int v = s_coact[i];
        if (v) atomicAdd(&ws[i], v);
    }
}

__global__ __launch_bounds__(256) void finalize_kernel(
    const int* __restrict__ ws,
    const float* __restrict__ ema_in,
    const float* __restrict__ coact_in,
    float* __restrict__ out)
{
    const int t = threadIdx.x;

    // Mirror upper-triangle ws into the full symmetric delta.
    // delta[i][j] (i!=j) = ws[min*64+max]; delta[i][i] = 2*ws[i*65]
    // (reference adds the diagonal twice: .at[a,b] and .at[b,a]).
    for (int c = t; c < NCELLS; c += 256) {
        const int i = c >> 6, j = c & 63;
        const int lo = min(i, j), hi = max(i, j);
        int d = ws[lo * NUM_EXPERTS + hi];
        if (i == j) d *= 2;
        out[NUM_EXPERTS + c] = coact_in[c] + (float)d;
    }

    // counts[e] = rowsum(delta[e][:]) / 3 exactly (each occurrence of e
    // pairs with the 3 other slots, duplicates included).
    if (t < NUM_EXPERTS) {
        int rowsum = 0;
        #pragma unroll
        for (int j = 0; j < NUM_EXPERTS; ++j) {
            const int lo = min(t, j), hi = max(t, j);
            int d = ws[lo * NUM_EXPERTS + hi];
            rowsum += (j == t) ? 2 * d : d;
        }
        const int count = rowsum / 3;
        const float load = (float)count / (float)N_TOKENS;
        out[t] = ema_in[t] * 0.99f + load * 0.01f;
    }
}

extern "C" void kernel_launch(void* const* d_in, const int* in_sizes, int n_in,
                              void* d_out, int out_size, void* d_ws, size_t ws_size,
                              hipStream_t stream)
{
    const int*   idx      = (const int*)d_in[0];
    // d_in[1] = expert_weights: unused by the reference -> never read (saves 32 MB).
    const float* ema_in   = (const float*)d_in[2];
    const float* coact_in = (const float*)d_in[3];
    float*       out      = (float*)d_out;
    int*         ws       = (int*)d_ws;

    // ws is poisoned 0xAA before every timed launch — zero the 16 KB we use.
    hipMemsetAsync(ws, 0, NCELLS * sizeof(int), stream);

    // 512 blocks x 256 threads: 2 blocks/CU (8 waves/CU), 16 tokens/thread.
    coact_accum_kernel<<<512, 256, 0, stream>>>(idx, ws);
    finalize_kernel<<<1, 256, 0, stream>>>(ws, ema_in, coact_in, out);
}